// Round 7
// baseline (251.229 us; speedup 1.0000x reference)
//
#include <hip/hip_runtime.h>
#include <math.h>

typedef unsigned short u16;
typedef unsigned int u32;
typedef __attribute__((ext_vector_type(8))) short short8;  // 8 bf16 (4 VGPR)
typedef __attribute__((ext_vector_type(4))) float f32x4;   // MFMA acc

#define DEVI __device__ __forceinline__

DEVI u16 f2bf(float x) {
    union { float f; u32 u; } un; un.f = x;
    u32 u = un.u;
    return (u16)((u + 0x7fffu + ((u >> 16) & 1u)) >> 16);  // RTNE
}
DEVI float bf2f(u16 v) {
    union { u32 u; float f; } un; un.u = ((u32)v) << 16;
    return un.f;
}
DEVI f32x4 mfma_bf16(short8 a, short8 b, f32x4 c) {
    return __builtin_amdgcn_mfma_f32_16x16x32_bf16(a, b, c, 0, 0, 0);
}
// async global->LDS, 16B/lane. LDS dest = wave-uniform base + lane*16.
DEVI void gload_lds16(const void* g, void* l) {
    __builtin_amdgcn_global_load_lds((const __attribute__((address_space(1))) u32*)g,
                                     (__attribute__((address_space(3))) u32*)l,
                                     16, 0, 0);
}

// transpose one 64x64 fp32 tile -> bf16 transposed, via padded LDS tile
DEVI void transpose_tile_64(const float* __restrict__ in, u16* __restrict__ out,
                            int R, int C, int bx, int by, int tidx, u16 (*tile)[68]) {
    const int tx = tidx & 15, ty = tidx >> 4;
    const long r0 = (long)by * 64, c0 = (long)bx * 64;
#pragma unroll
    for (int p = 0; p < 4; ++p) {
        int r = ty + p * 16;
        float4 v = *(const float4*)(in + (r0 + r) * C + c0 + tx * 4);
        ushort4 o;
        o.x = f2bf(v.x); o.y = f2bf(v.y); o.z = f2bf(v.z); o.w = f2bf(v.w);
        *(ushort4*)&tile[r][tx * 4] = o;
    }
    __syncthreads();
#pragma unroll
    for (int p = 0; p < 4; ++p) {
        int rr = ty + p * 16;
        ushort4 o;
        o.x = tile[tx * 4 + 0][rr];
        o.y = tile[tx * 4 + 1][rr];
        o.z = tile[tx * 4 + 2][rr];
        o.w = tile[tx * 4 + 3][rr];
        *(ushort4*)(out + (c0 + rr) * R + r0 + tx * 4) = o;
    }
}

// ---------------- prep: x->bf16 convert + Wqkv^T + Wout^T ----------------
// blocks [0,4096): convert; [4096,7168): Wqkv^T; [7168,8192): Wout^T
__global__ void k_prep(const float* __restrict__ x, const float* __restrict__ Wqkv,
                       const float* __restrict__ Wout, u16* __restrict__ x_bf,
                       u16* __restrict__ WqkvT, u16* __restrict__ WoutT) {
    __shared__ u16 tile[64][68];
    const int bid = blockIdx.x;
    if (bid < 4096) {
        long idx = ((long)bid * 256 + threadIdx.x) * 4;
        float4 v = *(const float4*)(x + idx);
        ushort4 o;
        o.x = f2bf(v.x); o.y = f2bf(v.y); o.z = f2bf(v.z); o.w = f2bf(v.w);
        *(ushort4*)(x_bf + idx) = o;
        return;
    }
    if (bid < 7168) {
        int lb = bid - 4096;
        transpose_tile_64(Wqkv, WqkvT, 2048, 6144, lb % 96, lb / 96, threadIdx.x, tile);
    } else {
        int lb = bid - 7168;
        transpose_tile_64(Wout, WoutT, 2048, 2048, lb & 31, lb >> 5, threadIdx.x, tile);
    }
}

// ---------------- QKV GEMM (m97-style, XOR-swizzled LDS, 128x128 tile) ----------------
// qkv = x_bf @ WqkvT^T; epilogue: RoPE q/k -> qb/kb, v transposed -> vT[32][128][1024]
__global__ __launch_bounds__(256, 3) void k_gemm_qkv(const u16* __restrict__ A,
                                                     const u16* __restrict__ BT,
                                                     u16* __restrict__ qb, u16* __restrict__ kb,
                                                     u16* __restrict__ vtb) {
    constexpr int K = 2048;
    __shared__ __align__(16) union SM {
        struct { u16 As[128 * 64]; u16 Bs[128 * 64]; } s;  // swizzled staging
        u16 T[128 * 132];                                  // epilogue tile (pad 132)
    } sm;
    const int tid = threadIdx.x;
    const int lane = tid & 63, wave = tid >> 6;
    const int lm = lane & 15, quad = lane >> 4;
    const int wm = wave >> 1, wn = wave & 1;
    const int bm = blockIdx.x, bn = blockIdx.y;

    f32x4 acc[4][4] = {};

    const int srow = lane >> 3;
    const int scb = (lane & 7) ^ srow;
    const long arow0 = (long)bm * 128;
    const long brow0 = (long)bn * 128;

    for (int k0 = 0; k0 < K; k0 += 64) {
        __syncthreads();
#pragma unroll
        for (int it = 0; it < 4; ++it) {
            int ch = wave * 4 + it;
            long r = ch * 8 + srow;
            gload_lds16(A + (arow0 + r) * K + k0 + scb * 8, (char*)sm.s.As + ch * 1024);
            gload_lds16(BT + (brow0 + r) * K + k0 + scb * 8, (char*)sm.s.Bs + ch * 1024);
        }
        __syncthreads();
#pragma unroll
        for (int ko = 0; ko < 2; ++ko) {
            short8 af[4], bf[4];
#pragma unroll
            for (int i = 0; i < 4; ++i) {
                int row = wm * 64 + i * 16 + lm;
                int pc = (ko * 4 + quad) ^ (lm & 7);
                af[i] = *(const short8*)&sm.s.As[row * 64 + pc * 8];
            }
#pragma unroll
            for (int j = 0; j < 4; ++j) {
                int row = wn * 64 + j * 16 + lm;
                int pc = (ko * 4 + quad) ^ (lm & 7);
                bf[j] = *(const short8*)&sm.s.Bs[row * 64 + pc * 8];
            }
#pragma unroll
            for (int i = 0; i < 4; ++i)
#pragma unroll
                for (int j = 0; j < 4; ++j)
                    acc[i][j] = mfma_bf16(af[i], bf[j], acc[i][j]);
        }
    }

    __syncthreads();  // all waves done reading As/Bs
#pragma unroll
    for (int i = 0; i < 4; ++i)
#pragma unroll
        for (int j = 0; j < 4; ++j) {
            const int col = wn * 64 + j * 16 + lm;
#pragma unroll
            for (int r = 0; r < 4; ++r) {
                const int row = wm * 64 + i * 16 + quad * 4 + r;
                sm.T[row * 132 + col] = f2bf(acc[i][j][r]);
            }
        }
    __syncthreads();
    const int which = bn >> 4, h = bn & 15, b = bm >> 3;
    const int p0 = (bm & 7) * 128;
    if (which < 2) {
        // RoPE + store to q/k buffer [bh][pos][128]
        u16* dst = which ? kb : qb;
        const long hb = ((long)(b * 16 + h)) * 1024;
        const int i0 = (tid * 4) & 63;   // c-invariant
        const int pb = tid >> 4;         // pos_l = c*16 + pb
        float inv[4];
#pragma unroll
        for (int e = 0; e < 4; ++e)
            inv[e] = exp2f(-(float)(i0 + e) * 0.20762050593045952f);  // log2(1e4)/64
#pragma unroll
        for (int c = 0; c < 8; ++c) {
            const int pos_l = c * 16 + pb;
            ushort4 cur = *(const ushort4*)&sm.T[pos_l * 132 + i0];
            ushort4 par = *(const ushort4*)&sm.T[pos_l * 132 + i0 + 64];
            const float pg = (float)(p0 + pos_l);
            ushort4 o1, o2;
            const u16* cp = (const u16*)&cur;
            const u16* pp = (const u16*)&par;
            u16* o1p = (u16*)&o1;
            u16* o2p = (u16*)&o2;
#pragma unroll
            for (int e = 0; e < 4; ++e) {
                float th = pg * inv[e];
                float sv = __sinf(th), cv = __cosf(th);  // v_sin/v_cos, |th|<=1023
                float x1 = bf2f(cp[e]), x2 = bf2f(pp[e]);
                o1p[e] = f2bf(x1 * cv - x2 * sv);
                o2p[e] = f2bf(x2 * cv + x1 * sv);
            }
            const long rowb = (hb + p0 + pos_l) * 128;
            *(ushort4*)(dst + rowb + i0) = o1;
            *(ushort4*)(dst + rowb + i0 + 64) = o2;
        }
    } else {
        // V: store transposed into vT[32][128][1024]
        const long vrow = ((long)(b * 16 + h)) * 128;
#pragma unroll
        for (int c = 0; c < 8; ++c) {
            const int lin = c * 2048 + tid * 8;
            const int dk = lin >> 7;
            const int ps = lin & 127;
            ushort4 o1, o2;
            u16* o1p = (u16*)&o1;
            u16* o2p = (u16*)&o2;
#pragma unroll
            for (int e = 0; e < 4; ++e) {
                o1p[e] = sm.T[(ps + e) * 132 + dk];
                o2p[e] = sm.T[(ps + 4 + e) * 132 + dk];
            }
            u16* dst = vtb + (vrow + dk) * 1024 + p0 + ps;
            *(ushort4*)dst = o1;
            *(ushort4*)(dst + 4) = o2;
        }
    }
}

// ---------------- out-projection GEMM: out = rbuf @ WoutT^T + bias (fp32) ----------------
// 64x128 tiles -> grid 32x16 = 512 blocks (2/CU)
__global__ __launch_bounds__(256, 3) void k_gemm_out(const u16* __restrict__ A,
                                                     const u16* __restrict__ BT,
                                                     float* __restrict__ out,
                                                     const float* __restrict__ bias) {
    constexpr int K = 2048;
    __shared__ __align__(16) struct { u16 As[64 * 64]; u16 Bs[128 * 64]; } sm;
    const int tid = threadIdx.x;
    const int lane = tid & 63, wave = tid >> 6;
    const int lm = lane & 15, quad = lane >> 4;
    const int wm = wave >> 1, wn = wave & 1;
    const int bm = blockIdx.x, bn = blockIdx.y;

    f32x4 acc[2][4] = {};

    const int srow = lane >> 3;
    const int scb = (lane & 7) ^ srow;
    const long arow0 = (long)bm * 64;
    const long brow0 = (long)bn * 128;

    for (int k0 = 0; k0 < K; k0 += 64) {
        __syncthreads();
#pragma unroll
        for (int it = 0; it < 2; ++it) {
            int ch = wave * 2 + it;
            long r = ch * 8 + srow;
            gload_lds16(A + (arow0 + r) * K + k0 + scb * 8, (char*)sm.As + ch * 1024);
        }
#pragma unroll
        for (int it = 0; it < 4; ++it) {
            int ch = wave * 4 + it;
            long r = ch * 8 + srow;
            gload_lds16(BT + (brow0 + r) * K + k0 + scb * 8, (char*)sm.Bs + ch * 1024);
        }
        __syncthreads();
#pragma unroll
        for (int ko = 0; ko < 2; ++ko) {
            short8 af[2], bf[4];
#pragma unroll
            for (int i = 0; i < 2; ++i) {
                int row = wm * 32 + i * 16 + lm;
                int pc = (ko * 4 + quad) ^ (lm & 7);
                af[i] = *(const short8*)&sm.As[row * 64 + pc * 8];
            }
#pragma unroll
            for (int j = 0; j < 4; ++j) {
                int row = wn * 64 + j * 16 + lm;
                int pc = (ko * 4 + quad) ^ (lm & 7);
                bf[j] = *(const short8*)&sm.Bs[row * 64 + pc * 8];
            }
#pragma unroll
            for (int i = 0; i < 2; ++i)
#pragma unroll
                for (int j = 0; j < 4; ++j)
                    acc[i][j] = mfma_bf16(af[i], bf[j], acc[i][j]);
        }
    }

    float bv[4];
#pragma unroll
    for (int j = 0; j < 4; ++j) bv[j] = bias[bn * 128 + wn * 64 + j * 16 + lm];
#pragma unroll
    for (int i = 0; i < 2; ++i) {
#pragma unroll
        for (int r = 0; r < 4; ++r) {
            const int row = bm * 64 + wm * 32 + i * 16 + quad * 4 + r;
#pragma unroll
            for (int j = 0; j < 4; ++j) {
                const int col = bn * 128 + wn * 64 + j * 16 + lm;
                out[(long)row * 2048 + col] = acc[i][j][r] + bv[j];
            }
        }
    }
}

// ---------------- flash attention (causal), S^T = K*Q^T, swizzled LDS ----------------
// Dispatch-order-robust balance: id = bh*16 + j, qt = (j&1) ? 15-(j>>1) : (j>>1);
// adjacent ids alternate light/heavy so any contiguous CU assignment is balanced.
__global__ __launch_bounds__(256, 3) void k_flash(const u16* __restrict__ Q,
                                                  const u16* __restrict__ Kb,
                                                  const u16* __restrict__ VT,
                                                  u16* __restrict__ R) {
    __shared__ u16 Ks[64 * 128];  // [key 64][d 128], swizzled mask 15
    __shared__ u16 Vs[128 * 64];  // [d 128][key 64], swizzled mask 7
    __shared__ u16 Ps[64 * 72];   // [q 64][key 64 + 8 pad]
    const int tid = threadIdx.x;
    const int lane = tid & 63, wave = tid >> 6;
    const int lm = lane & 15, quad = lane >> 4;
    const int id = blockIdx.x;
    const int bh = id >> 4, j = id & 15;
    const int qt = (j & 1) ? (15 - (j >> 1)) : (j >> 1);
    const long qkbase = (long)bh * 1024 * 128;
    const long vtbase = (long)bh * 128 * 1024;
    const int q0 = qt * 64;

    short8 qf[4];
    {
        const u16* qrow = Q + qkbase + (long)(q0 + wave * 16 + lm) * 128 + quad * 8;
#pragma unroll
        for (int kc = 0; kc < 4; ++kc) qf[kc] = *(const short8*)(qrow + kc * 32);
    }

    f32x4 o_acc[8] = {};
    float m_i = -INFINITY, l_i = 0.f;
    const float cl2e = 0.08838834764831845f * 1.4426950408889634f;  // 1/sqrt(128)*log2(e)

    const int kr = lane >> 4;
    const int vr = lane >> 3;
    const int vcb = (lane & 7) ^ vr;

    for (int kt = 0; kt <= qt; ++kt) {
        __syncthreads();
        {
#pragma unroll
            for (int it = 0; it < 4; ++it) {
                int ch = wave * 4 + it;
                int krow = ch * 4 + kr;
                int kchunk = (lane & 15) ^ (krow & 15);
                gload_lds16(Kb + qkbase + (long)(kt * 64 + krow) * 128 + kchunk * 8,
                            (char*)Ks + ch * 1024);
                int vrow = ch * 8 + vr;
                gload_lds16(VT + vtbase + (long)vrow * 1024 + kt * 64 + vcb * 8,
                            (char*)Vs + ch * 1024);
            }
        }
        __syncthreads();

        f32x4 s_acc[4] = {};
#pragma unroll
        for (int kc = 0; kc < 4; ++kc) {
#pragma unroll
            for (int mi = 0; mi < 4; ++mi) {
                int row = mi * 16 + lm;
                int pc = (kc * 4 + quad) ^ lm;
                short8 ak = *(const short8*)&Ks[row * 128 + pc * 8];
                s_acc[mi] = mfma_bf16(ak, qf[kc], s_acc[mi]);
            }
        }
        float t[4][4];
        float cmax = -INFINITY;
        if (kt == qt) {  // only the diagonal tile needs masking
            const int qg = q0 + wave * 16 + lm;
#pragma unroll
            for (int mi = 0; mi < 4; ++mi)
#pragma unroll
                for (int r = 0; r < 4; ++r) {
                    int kg = kt * 64 + mi * 16 + quad * 4 + r;
                    float val = (kg <= qg) ? s_acc[mi][r] * cl2e : -INFINITY;
                    t[mi][r] = val;
                    cmax = fmaxf(cmax, val);
                }
        } else {
#pragma unroll
            for (int mi = 0; mi < 4; ++mi)
#pragma unroll
                for (int r = 0; r < 4; ++r) {
                    float val = s_acc[mi][r] * cl2e;
                    t[mi][r] = val;
                    cmax = fmaxf(cmax, val);
                }
        }
        cmax = fmaxf(cmax, __shfl_xor(cmax, 16));
        cmax = fmaxf(cmax, __shfl_xor(cmax, 32));
        float m_new = fmaxf(m_i, cmax);
        float alpha = exp2f(m_i - m_new);
        float csum = 0.f;
#pragma unroll
        for (int mi = 0; mi < 4; ++mi)
#pragma unroll
            for (int r = 0; r < 4; ++r) {
                float p = exp2f(t[mi][r] - m_new);
                t[mi][r] = p;
                csum += p;
            }
        csum += __shfl_xor(csum, 16);
        csum += __shfl_xor(csum, 32);
        l_i = l_i * alpha + csum;
        m_i = m_new;
#pragma unroll
        for (int mi = 0; mi < 4; ++mi) {
            ushort4 pk;
            pk.x = f2bf(t[mi][0]); pk.y = f2bf(t[mi][1]);
            pk.z = f2bf(t[mi][2]); pk.w = f2bf(t[mi][3]);
            *(ushort4*)&Ps[(wave * 16 + lm) * 72 + mi * 16 + quad * 4] = pk;
        }
        float aq[4];
#pragma unroll
        for (int r = 0; r < 4; ++r) aq[r] = __shfl(alpha, quad * 4 + r, 64);
#pragma unroll
        for (int nt = 0; nt < 8; ++nt)
#pragma unroll
            for (int r = 0; r < 4; ++r) o_acc[nt][r] *= aq[r];
        // O += P * V  (no barrier: same-wave Ps RAW, DS in-order)
#pragma unroll
        for (int kc = 0; kc < 2; ++kc) {
            short8 ap = *(const short8*)&Ps[(wave * 16 + lm) * 72 + kc * 32 + quad * 8];
#pragma unroll
            for (int nt = 0; nt < 8; ++nt) {
                int row = nt * 16 + lm;
                int pc = (kc * 4 + quad) ^ (lm & 7);
                short8 bv = *(const short8*)&Vs[row * 64 + pc * 8];
                o_acc[nt] = mfma_bf16(ap, bv, o_acc[nt]);
            }
        }
    }
    float lq[4];
#pragma unroll
    for (int r = 0; r < 4; ++r) lq[r] = __shfl(l_i, quad * 4 + r, 64);
    const int b = bh >> 4, h = bh & 15;
#pragma unroll
    for (int nt = 0; nt < 8; ++nt)
#pragma unroll
        for (int r = 0; r < 4; ++r) {
            const int pos = q0 + wave * 16 + quad * 4 + r;
            const int col = h * 128 + nt * 16 + lm;
            R[((long)b * 1024 + pos) * 2048 + col] = f2bf(o_acc[nt][r] / lq[r]);
        }
}

extern "C" void kernel_launch(void* const* d_in, const int* in_sizes, int n_in,
                              void* d_out, int out_size, void* d_ws, size_t ws_size,
                              hipStream_t stream) {
    const float* x    = (const float*)d_in[0];
    const float* Wqkv = (const float*)d_in[2];
    const float* Wout = (const float*)d_in[3];
    const float* bout = (const float*)d_in[4];
    float* out = (float*)d_out;

    char* ws = (char*)d_ws;
    u16* x_bf  = (u16*)(ws);                 // 8MB; dead after qkv GEMM
    u16* rbuf  = x_bf;                       // reuse: written by flash
    u16* WqkvT = (u16*)(ws + (8L << 20));    // 24MB
    u16* WoutT = (u16*)(ws + (32L << 20));   // 8MB
    u16* qbuf  = (u16*)(ws + (40L << 20));   // 8MB (roped)
    u16* kbuf  = (u16*)(ws + (48L << 20));   // 8MB (roped)
    u16* vtbuf = (u16*)(ws + (56L << 20));   // 8MB, vT[32][128][1024]

    k_prep<<<8192, 256, 0, stream>>>(x, Wqkv, Wout, x_bf, WqkvT, WoutT);
    k_gemm_qkv<<<dim3(16, 48), 256, 0, stream>>>(x_bf, WqkvT, qbuf, kbuf, vtbuf);
    k_flash<<<512, 256, 0, stream>>>(qbuf, kbuf, vtbuf, rbuf);
    k_gemm_out<<<dim3(32, 16), 256, 0, stream>>>(rbuf, WoutT, out, bout);
}

// Round 8
// 247.547 us; speedup vs baseline: 1.0149x; 1.0149x over previous
//
#include <hip/hip_runtime.h>
#include <math.h>

typedef unsigned short u16;
typedef unsigned int u32;
typedef __attribute__((ext_vector_type(8))) short short8;  // 8 bf16 (4 VGPR)
typedef __attribute__((ext_vector_type(4))) float f32x4;   // MFMA acc

#define DEVI __device__ __forceinline__

DEVI u16 f2bf(float x) {
    union { float f; u32 u; } un; un.f = x;
    u32 u = un.u;
    return (u16)((u + 0x7fffu + ((u >> 16) & 1u)) >> 16);  // RTNE
}
DEVI float bf2f(u16 v) {
    union { u32 u; float f; } un; un.u = ((u32)v) << 16;
    return un.f;
}
DEVI f32x4 mfma_bf16(short8 a, short8 b, f32x4 c) {
    return __builtin_amdgcn_mfma_f32_16x16x32_bf16(a, b, c, 0, 0, 0);
}
// async global->LDS, 16B/lane. LDS dest = wave-uniform base + lane*16.
DEVI void gload_lds16(const void* g, void* l) {
    __builtin_amdgcn_global_load_lds((const __attribute__((address_space(1))) u32*)g,
                                     (__attribute__((address_space(3))) u32*)l,
                                     16, 0, 0);
}

// transpose one 64x64 fp32 tile -> bf16 transposed, via padded LDS tile
DEVI void transpose_tile_64(const float* __restrict__ in, u16* __restrict__ out,
                            int R, int C, int bx, int by, int tidx, u16 (*tile)[68]) {
    const int tx = tidx & 15, ty = tidx >> 4;
    const long r0 = (long)by * 64, c0 = (long)bx * 64;
#pragma unroll
    for (int p = 0; p < 4; ++p) {
        int r = ty + p * 16;
        float4 v = *(const float4*)(in + (r0 + r) * C + c0 + tx * 4);
        ushort4 o;
        o.x = f2bf(v.x); o.y = f2bf(v.y); o.z = f2bf(v.z); o.w = f2bf(v.w);
        *(ushort4*)&tile[r][tx * 4] = o;
    }
    __syncthreads();
#pragma unroll
    for (int p = 0; p < 4; ++p) {
        int rr = ty + p * 16;
        ushort4 o;
        o.x = tile[tx * 4 + 0][rr];
        o.y = tile[tx * 4 + 1][rr];
        o.z = tile[tx * 4 + 2][rr];
        o.w = tile[tx * 4 + 3][rr];
        *(ushort4*)(out + (c0 + rr) * R + r0 + tx * 4) = o;
    }
}

// ---------------- prep: x->bf16 convert + Wqkv^T + Wout^T ----------------
__global__ void k_prep(const float* __restrict__ x, const float* __restrict__ Wqkv,
                       const float* __restrict__ Wout, u16* __restrict__ x_bf,
                       u16* __restrict__ WqkvT, u16* __restrict__ WoutT) {
    __shared__ u16 tile[64][68];
    const int bid = blockIdx.x;
    if (bid < 4096) {
        long idx = ((long)bid * 256 + threadIdx.x) * 4;
        float4 v = *(const float4*)(x + idx);
        ushort4 o;
        o.x = f2bf(v.x); o.y = f2bf(v.y); o.z = f2bf(v.z); o.w = f2bf(v.w);
        *(ushort4*)(x_bf + idx) = o;
        return;
    }
    if (bid < 7168) {
        int lb = bid - 4096;
        transpose_tile_64(Wqkv, WqkvT, 2048, 6144, lb % 96, lb / 96, threadIdx.x, tile);
    } else {
        int lb = bid - 7168;
        transpose_tile_64(Wout, WoutT, 2048, 2048, lb & 31, lb >> 5, threadIdx.x, tile);
    }
}

// ---------------- QKV GEMM (m97-style, XOR-swizzled LDS, 128x128 tile) ----------------
__global__ __launch_bounds__(256, 3) void k_gemm_qkv(const u16* __restrict__ A,
                                                     const u16* __restrict__ BT,
                                                     u16* __restrict__ qb, u16* __restrict__ kb,
                                                     u16* __restrict__ vtb) {
    constexpr int K = 2048;
    __shared__ __align__(16) union SM {
        struct { u16 As[128 * 64]; u16 Bs[128 * 64]; } s;  // swizzled staging
        u16 T[128 * 132];                                  // epilogue tile (pad 132)
    } sm;
    const int tid = threadIdx.x;
    const int lane = tid & 63, wave = tid >> 6;
    const int lm = lane & 15, quad = lane >> 4;
    const int wm = wave >> 1, wn = wave & 1;
    const int bm = blockIdx.x, bn = blockIdx.y;

    f32x4 acc[4][4] = {};

    const int srow = lane >> 3;
    const int scb = (lane & 7) ^ srow;
    const long arow0 = (long)bm * 128;
    const long brow0 = (long)bn * 128;

    for (int k0 = 0; k0 < K; k0 += 64) {
        __syncthreads();
#pragma unroll
        for (int it = 0; it < 4; ++it) {
            int ch = wave * 4 + it;
            long r = ch * 8 + srow;
            gload_lds16(A + (arow0 + r) * K + k0 + scb * 8, (char*)sm.s.As + ch * 1024);
            gload_lds16(BT + (brow0 + r) * K + k0 + scb * 8, (char*)sm.s.Bs + ch * 1024);
        }
        __syncthreads();
#pragma unroll
        for (int ko = 0; ko < 2; ++ko) {
            short8 af[4], bf[4];
#pragma unroll
            for (int i = 0; i < 4; ++i) {
                int row = wm * 64 + i * 16 + lm;
                int pc = (ko * 4 + quad) ^ (lm & 7);
                af[i] = *(const short8*)&sm.s.As[row * 64 + pc * 8];
            }
#pragma unroll
            for (int j = 0; j < 4; ++j) {
                int row = wn * 64 + j * 16 + lm;
                int pc = (ko * 4 + quad) ^ (lm & 7);
                bf[j] = *(const short8*)&sm.s.Bs[row * 64 + pc * 8];
            }
#pragma unroll
            for (int i = 0; i < 4; ++i)
#pragma unroll
                for (int j = 0; j < 4; ++j)
                    acc[i][j] = mfma_bf16(af[i], bf[j], acc[i][j]);
        }
    }

    __syncthreads();  // all waves done reading As/Bs
#pragma unroll
    for (int i = 0; i < 4; ++i)
#pragma unroll
        for (int j = 0; j < 4; ++j) {
            const int col = wn * 64 + j * 16 + lm;
#pragma unroll
            for (int r = 0; r < 4; ++r) {
                const int row = wm * 64 + i * 16 + quad * 4 + r;
                sm.T[row * 132 + col] = f2bf(acc[i][j][r]);
            }
        }
    __syncthreads();
    const int which = bn >> 4, h = bn & 15, b = bm >> 3;
    const int p0 = (bm & 7) * 128;
    if (which < 2) {
        // RoPE + store to q/k buffer [bh][pos][128]
        u16* dst = which ? kb : qb;
        const long hb = ((long)(b * 16 + h)) * 1024;
        const int i0 = (tid * 4) & 63;   // c-invariant
        const int pb = tid >> 4;         // pos_l = c*16 + pb
        float inv[4];
#pragma unroll
        for (int e = 0; e < 4; ++e)
            inv[e] = exp2f(-(float)(i0 + e) * 0.20762050593045952f);  // log2(1e4)/64
#pragma unroll
        for (int c = 0; c < 8; ++c) {
            const int pos_l = c * 16 + pb;
            ushort4 cur = *(const ushort4*)&sm.T[pos_l * 132 + i0];
            ushort4 par = *(const ushort4*)&sm.T[pos_l * 132 + i0 + 64];
            const float pg = (float)(p0 + pos_l);
            ushort4 o1, o2;
            const u16* cp = (const u16*)&cur;
            const u16* pp = (const u16*)&par;
            u16* o1p = (u16*)&o1;
            u16* o2p = (u16*)&o2;
#pragma unroll
            for (int e = 0; e < 4; ++e) {
                float th = pg * inv[e];
                float sv = __sinf(th), cv = __cosf(th);  // v_sin/v_cos, |th|<=1023
                float x1 = bf2f(cp[e]), x2 = bf2f(pp[e]);
                o1p[e] = f2bf(x1 * cv - x2 * sv);
                o2p[e] = f2bf(x2 * cv + x1 * sv);
            }
            const long rowb = (hb + p0 + pos_l) * 128;
            *(ushort4*)(dst + rowb + i0) = o1;
            *(ushort4*)(dst + rowb + i0 + 64) = o2;
        }
    } else {
        // V: store transposed into vT[32][128][1024]
        const long vrow = ((long)(b * 16 + h)) * 128;
#pragma unroll
        for (int c = 0; c < 8; ++c) {
            const int lin = c * 2048 + tid * 8;
            const int dk = lin >> 7;
            const int ps = lin & 127;
            ushort4 o1, o2;
            u16* o1p = (u16*)&o1;
            u16* o2p = (u16*)&o2;
#pragma unroll
            for (int e = 0; e < 4; ++e) {
                o1p[e] = sm.T[(ps + e) * 132 + dk];
                o2p[e] = sm.T[(ps + 4 + e) * 132 + dk];
            }
            u16* dst = vtb + (vrow + dk) * 1024 + p0 + ps;
            *(ushort4*)dst = o1;
            *(ushort4*)(dst + 4) = o2;
        }
    }
}

// ---------------- out-projection GEMM: out = rbuf @ WoutT^T + bias (fp32) ----------------
__global__ __launch_bounds__(256, 3) void k_gemm_out(const u16* __restrict__ A,
                                                     const u16* __restrict__ BT,
                                                     float* __restrict__ out,
                                                     const float* __restrict__ bias) {
    constexpr int K = 2048;
    __shared__ __align__(16) struct { u16 As[64 * 64]; u16 Bs[128 * 64]; } sm;
    const int tid = threadIdx.x;
    const int lane = tid & 63, wave = tid >> 6;
    const int lm = lane & 15, quad = lane >> 4;
    const int wm = wave >> 1, wn = wave & 1;
    const int bm = blockIdx.x, bn = blockIdx.y;

    f32x4 acc[2][4] = {};

    const int srow = lane >> 3;
    const int scb = (lane & 7) ^ srow;
    const long arow0 = (long)bm * 64;
    const long brow0 = (long)bn * 128;

    for (int k0 = 0; k0 < K; k0 += 64) {
        __syncthreads();
#pragma unroll
        for (int it = 0; it < 2; ++it) {
            int ch = wave * 2 + it;
            long r = ch * 8 + srow;
            gload_lds16(A + (arow0 + r) * K + k0 + scb * 8, (char*)sm.As + ch * 1024);
        }
#pragma unroll
        for (int it = 0; it < 4; ++it) {
            int ch = wave * 4 + it;
            long r = ch * 8 + srow;
            gload_lds16(BT + (brow0 + r) * K + k0 + scb * 8, (char*)sm.Bs + ch * 1024);
        }
        __syncthreads();
#pragma unroll
        for (int ko = 0; ko < 2; ++ko) {
            short8 af[2], bf[4];
#pragma unroll
            for (int i = 0; i < 2; ++i) {
                int row = wm * 32 + i * 16 + lm;
                int pc = (ko * 4 + quad) ^ (lm & 7);
                af[i] = *(const short8*)&sm.As[row * 64 + pc * 8];
            }
#pragma unroll
            for (int j = 0; j < 4; ++j) {
                int row = wn * 64 + j * 16 + lm;
                int pc = (ko * 4 + quad) ^ (lm & 7);
                bf[j] = *(const short8*)&sm.Bs[row * 64 + pc * 8];
            }
#pragma unroll
            for (int i = 0; i < 2; ++i)
#pragma unroll
                for (int j = 0; j < 4; ++j)
                    acc[i][j] = mfma_bf16(af[i], bf[j], acc[i][j]);
        }
    }

    float bv[4];
#pragma unroll
    for (int j = 0; j < 4; ++j) bv[j] = bias[bn * 128 + wn * 64 + j * 16 + lm];
#pragma unroll
    for (int i = 0; i < 2; ++i) {
#pragma unroll
        for (int r = 0; r < 4; ++r) {
            const int row = bm * 64 + wm * 32 + i * 16 + quad * 4 + r;
#pragma unroll
            for (int j = 0; j < 4; ++j) {
                const int col = bn * 128 + wn * 64 + j * 16 + lm;
                out[(long)row * 2048 + col] = acc[i][j][r] + bv[j];
            }
        }
    }
}

// ---------------- flash attention (causal), S^T = K*Q^T, swizzled LDS ----------------
// g-mapping: co-resident pair (id, id+256) -> qt = s and 15-s (sum 15).
// Measured R5 vs R7: HW assigns blocks ~ id mod 256, so this pairing balances load.
__global__ __launch_bounds__(256, 3) void k_flash(const u16* __restrict__ Q,
                                                  const u16* __restrict__ Kb,
                                                  const u16* __restrict__ VT,
                                                  u16* __restrict__ R) {
    __shared__ u16 Ks[64 * 128];  // [key 64][d 128], swizzled mask 15
    __shared__ u16 Vs[128 * 64];  // [d 128][key 64], swizzled mask 7
    __shared__ u16 Ps[64 * 72];   // [q 64][key 64 + 8 pad]
    const int tid = threadIdx.x;
    const int lane = tid & 63, wave = tid >> 6;
    const int lm = lane & 15, quad = lane >> 4;
    const int id = blockIdx.x;
    const int g = id >> 8, rem = id & 255;
    const int bh = rem >> 3, s = rem & 7;
    const int qt = g ? (15 - s) : s;
    const long qkbase = (long)bh * 1024 * 128;
    const long vtbase = (long)bh * 128 * 1024;
    const int q0 = qt * 64;

    short8 qf[4];
    {
        const u16* qrow = Q + qkbase + (long)(q0 + wave * 16 + lm) * 128 + quad * 8;
#pragma unroll
        for (int kc = 0; kc < 4; ++kc) qf[kc] = *(const short8*)(qrow + kc * 32);
    }

    f32x4 o_acc[8] = {};
    float m_i = -INFINITY, l_i = 0.f;
    const float cl2e = 0.08838834764831845f * 1.4426950408889634f;  // 1/sqrt(128)*log2(e)

    const int kr = lane >> 4;
    const int vr = lane >> 3;
    const int vcb = (lane & 7) ^ vr;

    for (int kt = 0; kt <= qt; ++kt) {
        __syncthreads();
        {
#pragma unroll
            for (int it = 0; it < 4; ++it) {
                int ch = wave * 4 + it;
                int krow = ch * 4 + kr;
                int kchunk = (lane & 15) ^ (krow & 15);
                gload_lds16(Kb + qkbase + (long)(kt * 64 + krow) * 128 + kchunk * 8,
                            (char*)Ks + ch * 1024);
                int vrow = ch * 8 + vr;
                gload_lds16(VT + vtbase + (long)vrow * 1024 + kt * 64 + vcb * 8,
                            (char*)Vs + ch * 1024);
            }
        }
        __syncthreads();

        f32x4 s_acc[4] = {};
#pragma unroll
        for (int kc = 0; kc < 4; ++kc) {
#pragma unroll
            for (int mi = 0; mi < 4; ++mi) {
                int row = mi * 16 + lm;
                int pc = (kc * 4 + quad) ^ lm;
                short8 ak = *(const short8*)&Ks[row * 128 + pc * 8];
                s_acc[mi] = mfma_bf16(ak, qf[kc], s_acc[mi]);
            }
        }
        float t[4][4];
        float cmax = -INFINITY;
        if (kt == qt) {  // only the diagonal tile needs masking
            const int qg = q0 + wave * 16 + lm;
#pragma unroll
            for (int mi = 0; mi < 4; ++mi)
#pragma unroll
                for (int r = 0; r < 4; ++r) {
                    int kg = kt * 64 + mi * 16 + quad * 4 + r;
                    float val = (kg <= qg) ? s_acc[mi][r] * cl2e : -INFINITY;
                    t[mi][r] = val;
                    cmax = fmaxf(cmax, val);
                }
        } else {
#pragma unroll
            for (int mi = 0; mi < 4; ++mi)
#pragma unroll
                for (int r = 0; r < 4; ++r) {
                    float val = s_acc[mi][r] * cl2e;
                    t[mi][r] = val;
                    cmax = fmaxf(cmax, val);
                }
        }
        cmax = fmaxf(cmax, __shfl_xor(cmax, 16));
        cmax = fmaxf(cmax, __shfl_xor(cmax, 32));
        float m_new = fmaxf(m_i, cmax);
        float alpha = exp2f(m_i - m_new);
        float csum = 0.f;
#pragma unroll
        for (int mi = 0; mi < 4; ++mi)
#pragma unroll
            for (int r = 0; r < 4; ++r) {
                float p = exp2f(t[mi][r] - m_new);
                t[mi][r] = p;
                csum += p;
            }
        csum += __shfl_xor(csum, 16);
        csum += __shfl_xor(csum, 32);
        l_i = l_i * alpha + csum;
        m_i = m_new;
#pragma unroll
        for (int mi = 0; mi < 4; ++mi) {
            ushort4 pk;
            pk.x = f2bf(t[mi][0]); pk.y = f2bf(t[mi][1]);
            pk.z = f2bf(t[mi][2]); pk.w = f2bf(t[mi][3]);
            *(ushort4*)&Ps[(wave * 16 + lm) * 72 + mi * 16 + quad * 4] = pk;
        }
        float aq[4];
#pragma unroll
        for (int r = 0; r < 4; ++r) aq[r] = __shfl(alpha, quad * 4 + r, 64);
#pragma unroll
        for (int nt = 0; nt < 8; ++nt)
#pragma unroll
            for (int r = 0; r < 4; ++r) o_acc[nt][r] *= aq[r];
        // O += P * V  (no barrier: same-wave Ps RAW, DS in-order)
#pragma unroll
        for (int kc = 0; kc < 2; ++kc) {
            short8 ap = *(const short8*)&Ps[(wave * 16 + lm) * 72 + kc * 32 + quad * 8];
#pragma unroll
            for (int nt = 0; nt < 8; ++nt) {
                int row = nt * 16 + lm;
                int pc = (kc * 4 + quad) ^ (lm & 7);
                short8 bv = *(const short8*)&Vs[row * 64 + pc * 8];
                o_acc[nt] = mfma_bf16(ap, bv, o_acc[nt]);
            }
        }
    }
    float lq[4];
#pragma unroll
    for (int r = 0; r < 4; ++r) lq[r] = __shfl(l_i, quad * 4 + r, 64);
    const int b = bh >> 4, h = bh & 15;
#pragma unroll
    for (int nt = 0; nt < 8; ++nt)
#pragma unroll
        for (int r = 0; r < 4; ++r) {
            const int pos = q0 + wave * 16 + quad * 4 + r;
            const int col = h * 128 + nt * 16 + lm;
            R[((long)b * 1024 + pos) * 2048 + col] = f2bf(o_acc[nt][r] / lq[r]);
        }
}

extern "C" void kernel_launch(void* const* d_in, const int* in_sizes, int n_in,
                              void* d_out, int out_size, void* d_ws, size_t ws_size,
                              hipStream_t stream) {
    const float* x    = (const float*)d_in[0];
    const float* Wqkv = (const float*)d_in[2];
    const float* Wout = (const float*)d_in[3];
    const float* bout = (const float*)d_in[4];
    float* out = (float*)d_out;

    char* ws = (char*)d_ws;
    u16* x_bf  = (u16*)(ws);                 // 8MB; dead after qkv GEMM
    u16* rbuf  = x_bf;                       // reuse: written by flash
    u16* WqkvT = (u16*)(ws + (8L << 20));    // 24MB
    u16* WoutT = (u16*)(ws + (32L << 20));   // 8MB
    u16* qbuf  = (u16*)(ws + (40L << 20));   // 8MB (roped)
    u16* kbuf  = (u16*)(ws + (48L << 20));   // 8MB (roped)
    u16* vtbuf = (u16*)(ws + (56L << 20));   // 8MB, vT[32][128][1024]

    k_prep<<<8192, 256, 0, stream>>>(x, Wqkv, Wout, x_bf, WqkvT, WoutT);
    k_gemm_qkv<<<dim3(16, 48), 256, 0, stream>>>(x_bf, WqkvT, qbuf, kbuf, vtbuf);
    k_flash<<<512, 256, 0, stream>>>(qbuf, kbuf, vtbuf, rbuf);
    k_gemm_out<<<dim3(32, 16), 256, 0, stream>>>(rbuf, WoutT, out, bout);
}

// Round 9
// 242.770 us; speedup vs baseline: 1.0348x; 1.0197x over previous
//
#include <hip/hip_runtime.h>
#include <math.h>

typedef unsigned short u16;
typedef unsigned int u32;
typedef __attribute__((ext_vector_type(8))) short short8;  // 8 bf16 (4 VGPR)
typedef __attribute__((ext_vector_type(4))) float f32x4;   // MFMA acc

#define DEVI __device__ __forceinline__

DEVI u16 f2bf(float x) {
    union { float f; u32 u; } un; un.f = x;
    u32 u = un.u;
    return (u16)((u + 0x7fffu + ((u >> 16) & 1u)) >> 16);  // RTNE
}
DEVI float bf2f(u16 v) {
    union { u32 u; float f; } un; un.u = ((u32)v) << 16;
    return un.f;
}
DEVI f32x4 mfma_bf16(short8 a, short8 b, f32x4 c) {
    return __builtin_amdgcn_mfma_f32_16x16x32_bf16(a, b, c, 0, 0, 0);
}
// async global->LDS, 16B/lane. LDS dest = wave-uniform base + lane*16.
DEVI void gload_lds16(const void* g, void* l) {
    __builtin_amdgcn_global_load_lds((const __attribute__((address_space(1))) u32*)g,
                                     (__attribute__((address_space(3))) u32*)l,
                                     16, 0, 0);
}

// transpose one 64x64 fp32 tile -> bf16 transposed, via padded LDS tile
DEVI void transpose_tile_64(const float* __restrict__ in, u16* __restrict__ out,
                            int R, int C, int bx, int by, int tidx, u16 (*tile)[68]) {
    const int tx = tidx & 15, ty = tidx >> 4;
    const long r0 = (long)by * 64, c0 = (long)bx * 64;
#pragma unroll
    for (int p = 0; p < 4; ++p) {
        int r = ty + p * 16;
        float4 v = *(const float4*)(in + (r0 + r) * C + c0 + tx * 4);
        ushort4 o;
        o.x = f2bf(v.x); o.y = f2bf(v.y); o.z = f2bf(v.z); o.w = f2bf(v.w);
        *(ushort4*)&tile[r][tx * 4] = o;
    }
    __syncthreads();
#pragma unroll
    for (int p = 0; p < 4; ++p) {
        int rr = ty + p * 16;
        ushort4 o;
        o.x = tile[tx * 4 + 0][rr];
        o.y = tile[tx * 4 + 1][rr];
        o.z = tile[tx * 4 + 2][rr];
        o.w = tile[tx * 4 + 3][rr];
        *(ushort4*)(out + (c0 + rr) * R + r0 + tx * 4) = o;
    }
}

// ---------------- prep: x->bf16 convert + Wqkv^T + Wout^T ----------------
__global__ void k_prep(const float* __restrict__ x, const float* __restrict__ Wqkv,
                       const float* __restrict__ Wout, u16* __restrict__ x_bf,
                       u16* __restrict__ WqkvT, u16* __restrict__ WoutT) {
    __shared__ u16 tile[64][68];
    const int bid = blockIdx.x;
    if (bid < 4096) {
        long idx = ((long)bid * 256 + threadIdx.x) * 4;
        float4 v = *(const float4*)(x + idx);
        ushort4 o;
        o.x = f2bf(v.x); o.y = f2bf(v.y); o.z = f2bf(v.z); o.w = f2bf(v.w);
        *(ushort4*)(x_bf + idx) = o;
        return;
    }
    if (bid < 7168) {
        int lb = bid - 4096;
        transpose_tile_64(Wqkv, WqkvT, 2048, 6144, lb % 96, lb / 96, threadIdx.x, tile);
    } else {
        int lb = bid - 7168;
        transpose_tile_64(Wout, WoutT, 2048, 2048, lb & 31, lb >> 5, threadIdx.x, tile);
    }
}

// ---------------- QKV GEMM (m97-style, XOR-swizzled LDS, 128x128 tile) ----------------
// Unchanged K-loop (m99/m100: dbuf neutral at this occupancy).
__global__ __launch_bounds__(256, 3) void k_gemm_qkv(const u16* __restrict__ A,
                                                     const u16* __restrict__ BT,
                                                     u16* __restrict__ qb, u16* __restrict__ kb,
                                                     u16* __restrict__ vtb) {
    constexpr int K = 2048;
    __shared__ __align__(16) union SM {
        struct { u16 As[128 * 64]; u16 Bs[128 * 64]; } s;  // swizzled staging
        u16 T[128 * 132];                                  // epilogue tile (pad 132)
    } sm;
    const int tid = threadIdx.x;
    const int lane = tid & 63, wave = tid >> 6;
    const int lm = lane & 15, quad = lane >> 4;
    const int wm = wave >> 1, wn = wave & 1;
    const int bm = blockIdx.x, bn = blockIdx.y;

    f32x4 acc[4][4] = {};

    const int srow = lane >> 3;
    const int scb = (lane & 7) ^ srow;
    const long arow0 = (long)bm * 128;
    const long brow0 = (long)bn * 128;

    for (int k0 = 0; k0 < K; k0 += 64) {
        __syncthreads();
#pragma unroll
        for (int it = 0; it < 4; ++it) {
            int ch = wave * 4 + it;
            long r = ch * 8 + srow;
            gload_lds16(A + (arow0 + r) * K + k0 + scb * 8, (char*)sm.s.As + ch * 1024);
            gload_lds16(BT + (brow0 + r) * K + k0 + scb * 8, (char*)sm.s.Bs + ch * 1024);
        }
        __syncthreads();
#pragma unroll
        for (int ko = 0; ko < 2; ++ko) {
            short8 af[4], bf[4];
#pragma unroll
            for (int i = 0; i < 4; ++i) {
                int row = wm * 64 + i * 16 + lm;
                int pc = (ko * 4 + quad) ^ (lm & 7);
                af[i] = *(const short8*)&sm.s.As[row * 64 + pc * 8];
            }
#pragma unroll
            for (int j = 0; j < 4; ++j) {
                int row = wn * 64 + j * 16 + lm;
                int pc = (ko * 4 + quad) ^ (lm & 7);
                bf[j] = *(const short8*)&sm.s.Bs[row * 64 + pc * 8];
            }
#pragma unroll
            for (int i = 0; i < 4; ++i)
#pragma unroll
                for (int j = 0; j < 4; ++j)
                    acc[i][j] = mfma_bf16(af[i], bf[j], acc[i][j]);
        }
    }

    __syncthreads();  // all waves done reading As/Bs
#pragma unroll
    for (int i = 0; i < 4; ++i)
#pragma unroll
        for (int j = 0; j < 4; ++j) {
            const int col = wn * 64 + j * 16 + lm;
#pragma unroll
            for (int r = 0; r < 4; ++r) {
                const int row = wm * 64 + i * 16 + quad * 4 + r;
                sm.T[row * 132 + col] = f2bf(acc[i][j][r]);
            }
        }
    __syncthreads();
    const int which = bn >> 4, h = bn & 15, b = bm >> 3;
    const int p0 = (bm & 7) * 128;
    if (which < 2) {
        // RoPE + store to q/k buffer [bh][pos][128]
        u16* dst = which ? kb : qb;
        const long hb = ((long)(b * 16 + h)) * 1024;
        const int i0 = (tid * 4) & 63;   // c-invariant
        const int pb = tid >> 4;         // pos_l = c*16 + pb
        float inv[4];
#pragma unroll
        for (int e = 0; e < 4; ++e)
            inv[e] = exp2f(-(float)(i0 + e) * 0.20762050593045952f);  // log2(1e4)/64
#pragma unroll
        for (int c = 0; c < 8; ++c) {
            const int pos_l = c * 16 + pb;
            ushort4 cur = *(const ushort4*)&sm.T[pos_l * 132 + i0];
            ushort4 par = *(const ushort4*)&sm.T[pos_l * 132 + i0 + 64];
            const float pg = (float)(p0 + pos_l);
            ushort4 o1, o2;
            const u16* cp = (const u16*)&cur;
            const u16* pp = (const u16*)&par;
            u16* o1p = (u16*)&o1;
            u16* o2p = (u16*)&o2;
#pragma unroll
            for (int e = 0; e < 4; ++e) {
                float th = pg * inv[e];
                float sv = __sinf(th), cv = __cosf(th);  // v_sin/v_cos, |th|<=1023
                float x1 = bf2f(cp[e]), x2 = bf2f(pp[e]);
                o1p[e] = f2bf(x1 * cv - x2 * sv);
                o2p[e] = f2bf(x2 * cv + x1 * sv);
            }
            const long rowb = (hb + p0 + pos_l) * 128;
            *(ushort4*)(dst + rowb + i0) = o1;
            *(ushort4*)(dst + rowb + i0 + 64) = o2;
        }
    } else {
        // V: store transposed into vT[32][128][1024]
        const long vrow = ((long)(b * 16 + h)) * 128;
#pragma unroll
        for (int c = 0; c < 8; ++c) {
            const int lin = c * 2048 + tid * 8;
            const int dk = lin >> 7;
            const int ps = lin & 127;
            ushort4 o1, o2;
            u16* o1p = (u16*)&o1;
            u16* o2p = (u16*)&o2;
#pragma unroll
            for (int e = 0; e < 4; ++e) {
                o1p[e] = sm.T[(ps + e) * 132 + dk];
                o2p[e] = sm.T[(ps + 4 + e) * 132 + dk];
            }
            u16* dst = vtb + (vrow + dk) * 1024 + p0 + ps;
            *(ushort4*)dst = o1;
            *(ushort4*)(dst + 4) = o2;
        }
    }
}

// ---------------- out-projection GEMM, PIPELINED double-buffer staging ----------------
// out = rbuf @ WoutT^T + bias (fp32). One barrier/iter: barrier -> issue stage(k+1)
// into buf^1 -> compute buf. The barrier drains loads issued a full iter earlier.
__global__ __launch_bounds__(256, 2) void k_gemm_out(const u16* __restrict__ A,
                                                     const u16* __restrict__ BT,
                                                     float* __restrict__ out,
                                                     const float* __restrict__ bias) {
    constexpr int K = 2048;
    __shared__ __align__(16) struct { u16 As[2][64 * 64]; u16 Bs[2][128 * 64]; } sm;
    const int tid = threadIdx.x;
    const int lane = tid & 63, wave = tid >> 6;
    const int lm = lane & 15, quad = lane >> 4;
    const int wm = wave >> 1, wn = wave & 1;
    const int bm = blockIdx.x, bn = blockIdx.y;

    f32x4 acc[2][4] = {};

    const int srow = lane >> 3;
    const int scb = (lane & 7) ^ srow;
    const long arow0 = (long)bm * 64;
    const long brow0 = (long)bn * 128;

    auto stage = [&](int k0, int buf) {
#pragma unroll
        for (int it = 0; it < 2; ++it) {
            int ch = wave * 2 + it;
            long r = ch * 8 + srow;
            gload_lds16(A + (arow0 + r) * K + k0 + scb * 8, (char*)sm.As[buf] + ch * 1024);
        }
#pragma unroll
        for (int it = 0; it < 4; ++it) {
            int ch = wave * 4 + it;
            long r = ch * 8 + srow;
            gload_lds16(BT + (brow0 + r) * K + k0 + scb * 8, (char*)sm.Bs[buf] + ch * 1024);
        }
    };

    stage(0, 0);  // prologue prefetch
    for (int k0 = 0; k0 < K; k0 += 64) {
        const int cur = (k0 >> 6) & 1;
        __syncthreads();  // stage(k0) complete (issued last iter); prev readers of buf^1 done
        if (k0 + 64 < K) stage(k0 + 64, cur ^ 1);
#pragma unroll
        for (int ko = 0; ko < 2; ++ko) {
            short8 af[2], bf[4];
#pragma unroll
            for (int i = 0; i < 2; ++i) {
                int row = wm * 32 + i * 16 + lm;
                int pc = (ko * 4 + quad) ^ (lm & 7);
                af[i] = *(const short8*)&sm.As[cur][row * 64 + pc * 8];
            }
#pragma unroll
            for (int j = 0; j < 4; ++j) {
                int row = wn * 64 + j * 16 + lm;
                int pc = (ko * 4 + quad) ^ (lm & 7);
                bf[j] = *(const short8*)&sm.Bs[cur][row * 64 + pc * 8];
            }
#pragma unroll
            for (int i = 0; i < 2; ++i)
#pragma unroll
                for (int j = 0; j < 4; ++j)
                    acc[i][j] = mfma_bf16(af[i], bf[j], acc[i][j]);
        }
    }

    float bv[4];
#pragma unroll
    for (int j = 0; j < 4; ++j) bv[j] = bias[bn * 128 + wn * 64 + j * 16 + lm];
#pragma unroll
    for (int i = 0; i < 2; ++i) {
#pragma unroll
        for (int r = 0; r < 4; ++r) {
            const int row = bm * 64 + wm * 32 + i * 16 + quad * 4 + r;
#pragma unroll
            for (int j = 0; j < 4; ++j) {
                const int col = bn * 128 + wn * 64 + j * 16 + lm;
                out[(long)row * 2048 + col] = acc[i][j][r] + bv[j];
            }
        }
    }
}

// ---------------- flash attention (causal), PIPELINED double-buffer K/V staging ----------------
// g-mapping: co-resident pair (id, id+256) -> qt = s and 15-s (R5 vs R7 A/B: HW assigns
// blocks ~ id mod 256). One barrier/iter; K/V for tile kt+1 prefetched during tile kt.
__global__ __launch_bounds__(256, 2) void k_flash(const u16* __restrict__ Q,
                                                  const u16* __restrict__ Kb,
                                                  const u16* __restrict__ VT,
                                                  u16* __restrict__ R) {
    __shared__ u16 Ks[2][64 * 128];  // [key 64][d 128], swizzled mask 15
    __shared__ u16 Vs[2][128 * 64];  // [d 128][key 64], swizzled mask 7
    __shared__ u16 Ps[64 * 72];      // [q 64][key 64 + 8 pad]
    const int tid = threadIdx.x;
    const int lane = tid & 63, wave = tid >> 6;
    const int lm = lane & 15, quad = lane >> 4;
    const int id = blockIdx.x;
    const int g = id >> 8, rem = id & 255;
    const int bh = rem >> 3, s = rem & 7;
    const int qt = g ? (15 - s) : s;
    const long qkbase = (long)bh * 1024 * 128;
    const long vtbase = (long)bh * 128 * 1024;
    const int q0 = qt * 64;

    short8 qf[4];
    {
        const u16* qrow = Q + qkbase + (long)(q0 + wave * 16 + lm) * 128 + quad * 8;
#pragma unroll
        for (int kc = 0; kc < 4; ++kc) qf[kc] = *(const short8*)(qrow + kc * 32);
    }

    f32x4 o_acc[8] = {};
    float m_i = -INFINITY, l_i = 0.f;
    const float cl2e = 0.08838834764831845f * 1.4426950408889634f;  // 1/sqrt(128)*log2(e)

    const int kr = lane >> 4;
    const int vr = lane >> 3;
    const int vcb = (lane & 7) ^ vr;

    auto stage = [&](int kt, int buf) {
#pragma unroll
        for (int it = 0; it < 4; ++it) {
            int ch = wave * 4 + it;
            int krow = ch * 4 + kr;
            int kchunk = (lane & 15) ^ (krow & 15);
            gload_lds16(Kb + qkbase + (long)(kt * 64 + krow) * 128 + kchunk * 8,
                        (char*)Ks[buf] + ch * 1024);
            int vrow = ch * 8 + vr;
            gload_lds16(VT + vtbase + (long)vrow * 1024 + kt * 64 + vcb * 8,
                        (char*)Vs[buf] + ch * 1024);
        }
    };

    stage(0, 0);  // prologue prefetch
    for (int kt = 0; kt <= qt; ++kt) {
        const int cur = kt & 1;
        __syncthreads();  // stage(kt) complete (issued a full iter ago); buf^1 readers done
        if (kt < qt) stage(kt + 1, cur ^ 1);

        // S^T[key 64][q 16] = K * Q^T
        f32x4 s_acc[4] = {};
#pragma unroll
        for (int kc = 0; kc < 4; ++kc) {
#pragma unroll
            for (int mi = 0; mi < 4; ++mi) {
                int row = mi * 16 + lm;
                int pc = (kc * 4 + quad) ^ lm;
                short8 ak = *(const short8*)&Ks[cur][row * 128 + pc * 8];
                s_acc[mi] = mfma_bf16(ak, qf[kc], s_acc[mi]);
            }
        }
        float t[4][4];
        float cmax = -INFINITY;
        if (kt == qt) {  // only the diagonal tile needs masking
            const int qg = q0 + wave * 16 + lm;
#pragma unroll
            for (int mi = 0; mi < 4; ++mi)
#pragma unroll
                for (int r = 0; r < 4; ++r) {
                    int kg = kt * 64 + mi * 16 + quad * 4 + r;
                    float val = (kg <= qg) ? s_acc[mi][r] * cl2e : -INFINITY;
                    t[mi][r] = val;
                    cmax = fmaxf(cmax, val);
                }
        } else {
#pragma unroll
            for (int mi = 0; mi < 4; ++mi)
#pragma unroll
                for (int r = 0; r < 4; ++r) {
                    float val = s_acc[mi][r] * cl2e;
                    t[mi][r] = val;
                    cmax = fmaxf(cmax, val);
                }
        }
        cmax = fmaxf(cmax, __shfl_xor(cmax, 16));
        cmax = fmaxf(cmax, __shfl_xor(cmax, 32));
        float m_new = fmaxf(m_i, cmax);
        float alpha = exp2f(m_i - m_new);
        float csum = 0.f;
#pragma unroll
        for (int mi = 0; mi < 4; ++mi)
#pragma unroll
            for (int r = 0; r < 4; ++r) {
                float p = exp2f(t[mi][r] - m_new);
                t[mi][r] = p;
                csum += p;
            }
        csum += __shfl_xor(csum, 16);
        csum += __shfl_xor(csum, 32);
        l_i = l_i * alpha + csum;
        m_i = m_new;
#pragma unroll
        for (int mi = 0; mi < 4; ++mi) {
            ushort4 pk;
            pk.x = f2bf(t[mi][0]); pk.y = f2bf(t[mi][1]);
            pk.z = f2bf(t[mi][2]); pk.w = f2bf(t[mi][3]);
            *(ushort4*)&Ps[(wave * 16 + lm) * 72 + mi * 16 + quad * 4] = pk;
        }
        float aq[4];
#pragma unroll
        for (int r = 0; r < 4; ++r) aq[r] = __shfl(alpha, quad * 4 + r, 64);
#pragma unroll
        for (int nt = 0; nt < 8; ++nt)
#pragma unroll
            for (int r = 0; r < 4; ++r) o_acc[nt][r] *= aq[r];
        // O += P * V  (no barrier: same-wave Ps RAW, DS in-order)
#pragma unroll
        for (int kc = 0; kc < 2; ++kc) {
            short8 ap = *(const short8*)&Ps[(wave * 16 + lm) * 72 + kc * 32 + quad * 8];
#pragma unroll
            for (int nt = 0; nt < 8; ++nt) {
                int row = nt * 16 + lm;
                int pc = (kc * 4 + quad) ^ (lm & 7);
                short8 bv = *(const short8*)&Vs[cur][row * 64 + pc * 8];
                o_acc[nt] = mfma_bf16(ap, bv, o_acc[nt]);
            }
        }
    }
    float lq[4];
#pragma unroll
    for (int r = 0; r < 4; ++r) lq[r] = __shfl(l_i, quad * 4 + r, 64);
    const int b = bh >> 4, h = bh & 15;
#pragma unroll
    for (int nt = 0; nt < 8; ++nt)
#pragma unroll
        for (int r = 0; r < 4; ++r) {
            const int pos = q0 + wave * 16 + quad * 4 + r;
            const int col = h * 128 + nt * 16 + lm;
            R[((long)b * 1024 + pos) * 2048 + col] = f2bf(o_acc[nt][r] / lq[r]);
        }
}

extern "C" void kernel_launch(void* const* d_in, const int* in_sizes, int n_in,
                              void* d_out, int out_size, void* d_ws, size_t ws_size,
                              hipStream_t stream) {
    const float* x    = (const float*)d_in[0];
    const float* Wqkv = (const float*)d_in[2];
    const float* Wout = (const float*)d_in[3];
    const float* bout = (const float*)d_in[4];
    float* out = (float*)d_out;

    char* ws = (char*)d_ws;
    u16* x_bf  = (u16*)(ws);                 // 8MB; dead after qkv GEMM
    u16* rbuf  = x_bf;                       // reuse: written by flash
    u16* WqkvT = (u16*)(ws + (8L << 20));    // 24MB
    u16* WoutT = (u16*)(ws + (32L << 20));   // 8MB
    u16* qbuf  = (u16*)(ws + (40L << 20));   // 8MB (roped)
    u16* kbuf  = (u16*)(ws + (48L << 20));   // 8MB (roped)
    u16* vtbuf = (u16*)(ws + (56L << 20));   // 8MB, vT[32][128][1024]

    k_prep<<<8192, 256, 0, stream>>>(x, Wqkv, Wout, x_bf, WqkvT, WoutT);
    k_gemm_qkv<<<dim3(16, 48), 256, 0, stream>>>(x_bf, WqkvT, qbuf, kbuf, vtbuf);
    k_flash<<<512, 256, 0, stream>>>(qbuf, kbuf, vtbuf, rbuf);
    k_gemm_out<<<dim3(32, 16), 256, 0, stream>>>(rbuf, WoutT, out, bout);
}